// Round 7
// baseline (334.786 us; speedup 1.0000x reference)
//
#include <hip/hip_runtime.h>

// GCN N=100k, E=1.6M, H=64 — algebraic collapse + XCD-private atomic partials.
//
// Math (layer-1 input is [N,1] => per-node hidden state is a scalar function):
//   s[d] = dinv[d]*(sum_{src->d} dinv[src]*x[src] + dinv[d]*x[d])
//   relu(s*w1+b1) @ w2 = s*P^{sign(s)} + B^{sign(s)}   (P±,B± precomputed; B=0 when b1=0)
//   layer-2 scalars: a±[d] (sign-split sums of dinv_s*s_s), c±[d] (sums of dinv_s, B path)
//   out[d] = relu(dinv[d]*(a+P+ + a-P- + c+B+ + c-B-) + b2) . wfc + bfc
//
// Scatter strategy: every scatter-add target array is replicated 8x (one per XCD,
// 400KB each -> L2-resident). Each wave adds into replica[XCC_ID] (s_getreg,
// HW-verified gfx950). Lines of replica k are touched only by XCD k => atomics
// run at local-L2 speed, no cross-XCD line ping-pong (the round-3 failure mode).
// Node kernels reduce the 8 replicas with coalesced reads.
//
// Dispatches: memset -> k_deg -> k_dinv(+P fold) -> k_sagg -> k_mid -> k_l2 -> k_out.

#define HCH 64
#define NXCD 8

__device__ __forceinline__ int xcc_id() {
    int x;
    asm volatile("s_getreg_b32 %0, hwreg(HW_REG_XCC_ID)" : "=s"(x));
    return x & (NXCD - 1);
}

__device__ __forceinline__ void lds_addf(float* p, float v) {
    __hip_atomic_fetch_add(p, v, __ATOMIC_RELAXED, __HIP_MEMORY_SCOPE_WORKGROUP);
}

// edge pass 1: in-degree histogram into XCD-private replicas
__global__ __launch_bounds__(256) void k_deg(const int* __restrict__ dst, int e, int n,
                                             int* __restrict__ degp) {
    int* my = degp + xcc_id() * n;
    int i = (blockIdx.x * 256 + threadIdx.x) * 4;
    if (i + 3 < e) {
        int4 d = *(const int4*)(dst + i);
        atomicAdd(&my[d.x], 1);
        atomicAdd(&my[d.y], 1);
        atomicAdd(&my[d.z], 1);
        atomicAdd(&my[d.w], 1);
    } else {
        for (; i < e; i++) atomicAdd(&my[dst[i]], 1);
    }
}

// node pass: deg = sum of replicas -> dinv, y = dinv*x. Block 0 also computes
// P[0..63]=P+, P[64..127]=P-, P[128..191]=B+, P[192..255]=B-, P[256]=|B| flag.
__global__ __launch_bounds__(256) void k_dinv(const int* __restrict__ degp,
                                              const float* __restrict__ x, int n,
                                              float* __restrict__ dinv,
                                              float* __restrict__ y,
                                              const float* __restrict__ w1,
                                              const float* __restrict__ b1,
                                              const float* __restrict__ w2,
                                              float* __restrict__ P) {
    int i = blockIdx.x * 256 + threadIdx.x;
    if (i < n) {
        int d = 0;
#pragma unroll
        for (int k = 0; k < NXCD; k++) d += degp[k * n + i];
        float dv = rsqrtf((float)(d + 1));  // +1 self-loop
        dinv[i] = dv;
        y[i] = dv * x[i];
    }
    if (blockIdx.x == 0) {
        __shared__ float fs;
        int t = threadIdx.x;
        if (t == 0) fs = 0.f;
        __syncthreads();
        int c = t >> 6, j = t & 63;
        float acc = 0.f;
        for (int k = 0; k < HCH; k++) {
            float w = w1[k], b = b1[k], v = w2[k * HCH + j];
            if (c == 0)      acc += (w > 0.f) ? w * v : 0.f;
            else if (c == 1) acc += (w < 0.f) ? w * v : 0.f;
            else if (c == 2) acc += (w > 0.f) ? b * v : (w == 0.f ? fmaxf(b, 0.f) * v : 0.f);
            else             acc += (w < 0.f) ? b * v : (w == 0.f ? fmaxf(b, 0.f) * v : 0.f);
        }
        P[t] = acc;
        if (c >= 2) lds_addf(&fs, fabsf(acc));
        __syncthreads();
        if (t == 0) P[4 * HCH] = fs;
    }
}

// edge pass 2: s_agg[dst] += y[src] into XCD-private replicas
__global__ __launch_bounds__(256) void k_sagg(const int* __restrict__ src,
                                              const int* __restrict__ dst, int e, int n,
                                              const float* __restrict__ y,
                                              float* __restrict__ saggp) {
    float* my = saggp + xcc_id() * n;
    int i = (blockIdx.x * 256 + threadIdx.x) * 4;
    if (i + 3 < e) {
        int4 s4 = *(const int4*)(src + i);
        int4 d4 = *(const int4*)(dst + i);
        float y0 = y[s4.x], y1 = y[s4.y], y2 = y[s4.z], y3 = y[s4.w];
        atomicAdd(&my[d4.x], y0);
        atomicAdd(&my[d4.y], y1);
        atomicAdd(&my[d4.z], y2);
        atomicAdd(&my[d4.w], y3);
    } else {
        for (; i < e; i++) atomicAdd(&my[dst[i]], y[src[i]]);
    }
}

// node pass: s -> val2 = (dinv*s, dinv)
__global__ __launch_bounds__(256) void k_mid(const float* __restrict__ saggp,
                                             const float* __restrict__ x,
                                             const float* __restrict__ dinv, int n,
                                             float2* __restrict__ val2) {
    int i = blockIdx.x * 256 + threadIdx.x;
    if (i < n) {
        float sa = 0.f;
#pragma unroll
        for (int k = 0; k < NXCD; k++) sa += saggp[k * n + i];
        float dv = dinv[i];
        float s = dv * (sa + dv * x[i]);
        val2[i] = make_float2(dv * s, dv);
    }
}

// edge pass 3: sign-split a±[dst] += v.x (and c±[dst] += v.y iff B nonzero)
__global__ __launch_bounds__(256) void k_l2(const int* __restrict__ src,
                                            const int* __restrict__ dst, int e, int n,
                                            const float2* __restrict__ val2,
                                            const float* __restrict__ P,
                                            float* __restrict__ app, float* __restrict__ amp,
                                            float* __restrict__ cpp, float* __restrict__ cmp) {
    int off = xcc_id() * n;
    bool useB = P[4 * HCH] != 0.f;
    int i = (blockIdx.x * 256 + threadIdx.x) * 4;
    if (i + 3 < e) {
        int4 s4 = *(const int4*)(src + i);
        int4 d4 = *(const int4*)(dst + i);
        float2 v0 = val2[s4.x], v1 = val2[s4.y], v2 = val2[s4.z], v3 = val2[s4.w];
        atomicAdd((v0.x > 0.f ? app : amp) + off + d4.x, v0.x);
        atomicAdd((v1.x > 0.f ? app : amp) + off + d4.y, v1.x);
        atomicAdd((v2.x > 0.f ? app : amp) + off + d4.z, v2.x);
        atomicAdd((v3.x > 0.f ? app : amp) + off + d4.w, v3.x);
        if (useB) {
            atomicAdd((v0.x > 0.f ? cpp : cmp) + off + d4.x, v0.y);
            atomicAdd((v1.x > 0.f ? cpp : cmp) + off + d4.y, v1.y);
            atomicAdd((v2.x > 0.f ? cpp : cmp) + off + d4.z, v2.y);
            atomicAdd((v3.x > 0.f ? cpp : cmp) + off + d4.w, v3.y);
        }
    } else {
        for (; i < e; i++) {
            float2 v = val2[src[i]];
            int d = dst[i];
            atomicAdd((v.x > 0.f ? app : amp) + off + d, v.x);
            if (useB) atomicAdd((v.x > 0.f ? cpp : cmp) + off + d, v.y);
        }
    }
}

// node pass: reduce replicas + self-loop + fused epilogue -> out
__global__ __launch_bounds__(256) void k_out(const float* __restrict__ app,
                                             const float* __restrict__ amp,
                                             const float* __restrict__ cpp,
                                             const float* __restrict__ cmp,
                                             const float2* __restrict__ val2,
                                             const float* __restrict__ dinv,
                                             const float* __restrict__ P,
                                             const float* __restrict__ b2,
                                             const float* __restrict__ wfc,
                                             const float* __restrict__ bfc,
                                             float* __restrict__ out, int n) {
    __shared__ float sP[4 * HCH], sb2[HCH], swfc[HCH];
    int t = threadIdx.x;
    sP[t] = P[t];
    if (t < HCH) { sb2[t] = b2[t]; swfc[t] = wfc[t]; }
    __syncthreads();
    bool useB = P[4 * HCH] != 0.f;
    int i = blockIdx.x * 256 + t;
    if (i >= n) return;
    float a_p = 0.f, a_m = 0.f, c_p = 0.f, c_m = 0.f;
#pragma unroll
    for (int k = 0; k < NXCD; k++) {
        a_p += app[k * n + i];
        a_m += amp[k * n + i];
    }
    if (useB) {
#pragma unroll
        for (int k = 0; k < NXCD; k++) {
            c_p += cpp[k * n + i];
            c_m += cmp[k * n + i];
        }
    }
    float2 sv = val2[i];  // self-loop
    if (sv.x > 0.f) { a_p += sv.x; c_p += sv.y; }
    else            { a_m += sv.x; c_m += sv.y; }
    float dv = dinv[i];
    float acc = 0.f;
#pragma unroll 8
    for (int j = 0; j < HCH; j++) {
        float z = dv * (a_p * sP[j] + a_m * sP[HCH + j] +
                        c_p * sP[2 * HCH + j] + c_m * sP[3 * HCH + j]) + sb2[j];
        z = fmaxf(z, 0.f);
        acc += z * swfc[j];
    }
    out[i] = acc + bfc[0];
}

extern "C" void kernel_launch(void* const* d_in, const int* in_sizes, int n_in,
                              void* d_out, int out_size, void* d_ws, size_t ws_size,
                              hipStream_t stream) {
    const float* x   = (const float*)d_in[0];
    const int*   ei  = (const int*)d_in[1];
    const float* w1  = (const float*)d_in[2];
    const float* b1  = (const float*)d_in[3];
    const float* w2  = (const float*)d_in[4];
    const float* b2  = (const float*)d_in[5];
    const float* wfc = (const float*)d_in[6];
    const float* bfc = (const float*)d_in[7];
    float* out = (float*)d_out;

    const int n = in_sizes[0];      // 100000
    const int e = in_sizes[1] / 2;  // 1600000
    const int* src = ei;
    const int* dst = ei + e;

    auto al = [](size_t v) { return (v + 255) & ~(size_t)255; };
    char* ws = (char*)d_ws;
    size_t o = 0;
    int*   degp  = (int*)(ws + o);   o += (size_t)NXCD * n * 4;
    float* saggp = (float*)(ws + o); o += (size_t)NXCD * n * 4;
    float* app   = (float*)(ws + o); o += (size_t)NXCD * n * 4;
    float* amp   = (float*)(ws + o); o += (size_t)NXCD * n * 4;
    float* cpp   = (float*)(ws + o); o += (size_t)NXCD * n * 4;
    float* cmp   = (float*)(ws + o); o += (size_t)NXCD * n * 4;
    size_t zbytes = o;               // single memset covers all replicas (19.2MB)
    o = al(o);
    float* dinv  = (float*)(ws + o); o = al(o + (size_t)n * 4);
    float* y     = (float*)(ws + o); o = al(o + (size_t)n * 4);
    float2* val2 = (float2*)(ws + o); o = al(o + (size_t)n * 8);
    float* P     = (float*)(ws + o); o = al(o + (4 * HCH + 8) * 4);
    (void)ws_size;

    const int eb = ((e + 3) / 4 + 255) / 256;  // 1563 edge blocks (4 edges/thread)
    const int nb = (n + 255) / 256;            // 391 node blocks

    hipMemsetAsync(ws, 0, zbytes, stream);
    k_deg<<<eb, 256, 0, stream>>>(dst, e, n, degp);
    k_dinv<<<nb, 256, 0, stream>>>(degp, x, n, dinv, y, w1, b1, w2, P);
    k_sagg<<<eb, 256, 0, stream>>>(src, dst, e, n, y, saggp);
    k_mid<<<nb, 256, 0, stream>>>(saggp, x, dinv, n, val2);
    k_l2<<<eb, 256, 0, stream>>>(src, dst, e, n, val2, P, app, amp, cpp, cmp);
    k_out<<<nb, 256, 0, stream>>>(app, amp, cpp, cmp, val2, dinv, P,
                                  b2, wfc, bfc, out, n);
}

// Round 8
// 313.148 us; speedup vs baseline: 1.0691x; 1.0691x over previous
//
#include <hip/hip_runtime.h>
#include <hip/hip_cooperative_groups.h>

namespace cg = cooperative_groups;

// GCN N=100k, E=1.6M, H=64 — algebraic collapse + bucket-LDS scatter, fully
// fused into ONE cooperative kernel (grid.sync between phases).
//
// Math (layer-1 input is [N,1] => per-node hidden state is a scalar function):
//   s[d] = dinv[d]*(sum_{src->d} dinv[src]*x[src] + dinv[d]*x[d])
//   relu(s*w1+b1) @ w2 = s*P^{sign(s)} + B^{sign(s)}   (P±,B± 64-vecs; B=0 for b1=0)
//   layer-2 scalars a±[d], c±[d]; out = relu(dinv*(aP+ + aP- + cB+ + cB-) + b2).wfc + bfc
//
// Phases (one 391-block x 512-thread cooperative launch, all blocks co-resident):
//   1. place: bin edges by dst>>8 into fixed-cap bucket regions (LDS stash +
//      one cursor atomic per (chunk,bucket) run; exact overflow spill list)
//   2. bdeg: per-bucket LDS histogram -> dinv, y=dinv*x; block 0: P± precompute
//   3. bagg1: per-bucket LDS accumulate y[src] -> val2=(dinv*s, dinv)
//   4. bagg2: sign-split LDS accumulate of val2[src] + fused epilogue -> out
//
// Hard-won rule (rounds 3,7): global atomics = memory-side, ~60B/op equivalent;
// ALL scatter-accumulate must be LDS. XCD replicas do NOT help (device scope).

#define HCH 64
#define CHUNK 4096
#define BSH 8
#define BSZ 256          // nodes per bucket
#define NBMAX 512

__device__ __forceinline__ void lds_addf(float* p, float v) {
    __hip_atomic_fetch_add(p, v, __ATOMIC_RELAXED, __HIP_MEMORY_SCOPE_WORKGROUP);
}

union SMem {
    struct { int h[NBMAX]; int basel[NBMAX]; int avail[NBMAX];
             int lpv[CHUNK]; short lb[CHUNK]; } pl;                  // 30 KB
    struct { int cnt[BSZ]; } bd;
    struct { float acc[BSZ]; } g1;
    struct { float aa[2 * BSZ]; float cc[2 * BSZ];
             float sP[4 * HCH]; float sb2[HCH]; float swfc[HCH]; } g2;
};

__global__ __launch_bounds__(512, 4) void k_fused(
    const int* __restrict__ src, const int* __restrict__ dst, int e, int n,
    int nb, int nchunk, int cap,
    int* __restrict__ cursor, int* __restrict__ ov_cursor,
    int2* __restrict__ ovbuf, int* __restrict__ packed,
    const float* __restrict__ x, float* __restrict__ dinv,
    float* __restrict__ y, float2* __restrict__ val2,
    const float* __restrict__ w1, const float* __restrict__ b1,
    const float* __restrict__ w2, float* __restrict__ P,
    const float* __restrict__ b2v, const float* __restrict__ wfc,
    const float* __restrict__ bfc, float* __restrict__ out) {
    __shared__ SMem sm;
    cg::grid_group grid = cg::this_grid();
    int t = threadIdx.x;
    int bid = blockIdx.x;

    // ---------- phase 1: place ----------
    if (bid < nchunk) {
        for (int i = t; i < nb; i += 512) sm.pl.h[i] = 0;
        __syncthreads();
        int cbase = bid * CHUNK;
        int rem = min(e - cbase, CHUNK);
#pragma unroll
        for (int g = 0; g < 2; g++) {
            int li = t * 8 + g * 4;
            if (li + 3 < rem) {
                int4 s4 = *(const int4*)(src + cbase + li);
                int4 d4 = *(const int4*)(dst + cbase + li);
#pragma unroll
                for (int q = 0; q < 4; q++) {
                    int sv = (q == 0) ? s4.x : (q == 1) ? s4.y : (q == 2) ? s4.z : s4.w;
                    int dv = (q == 0) ? d4.x : (q == 1) ? d4.y : (q == 2) ? d4.z : d4.w;
                    int b = dv >> BSH;
                    atomicAdd(&sm.pl.h[b], 1);
                    sm.pl.lpv[li + q] = sv | ((dv & (BSZ - 1)) << 17);
                    sm.pl.lb[li + q] = (short)b;
                }
            } else {
                for (int q = li; q < rem && q < li + 4; q++) {
                    int sv = src[cbase + q], dv = dst[cbase + q];
                    int b = dv >> BSH;
                    atomicAdd(&sm.pl.h[b], 1);
                    sm.pl.lpv[q] = sv | ((dv & (BSZ - 1)) << 17);
                    sm.pl.lb[q] = (short)b;
                }
            }
        }
        __syncthreads();
        for (int i = t; i < nb; i += 512) {
            int my = sm.pl.h[i];
            int av = 0, base = 0;
            if (my) {
                base = atomicAdd(&cursor[i], my);   // bucket-relative
                int room = cap - base;
                av = room < 0 ? 0 : (room > my ? my : room);
            }
            sm.pl.basel[i] = i * cap + base;
            sm.pl.avail[i] = av;
            sm.pl.h[i] = 0;  // reuse as local run cursor
        }
        __syncthreads();
        int lim = min(rem, t * 8 + 8);
        for (int li = t * 8; li < lim; li++) {
            int b = sm.pl.lb[li];
            int pv = sm.pl.lpv[li];
            int loc = atomicAdd(&sm.pl.h[b], 1);
            if (loc < sm.pl.avail[b]) {
                packed[sm.pl.basel[b] + loc] = pv;
            } else {
                int op = atomicAdd(ov_cursor, 1);
                ovbuf[op] = make_int2(pv & 0x1FFFF, (b << BSH) | (pv >> 17));
            }
        }
    }
    grid.sync();

    // ---------- phase 2: bdeg -> dinv, y; block 0: P precompute ----------
    if (bid < nb) {
        if (t < BSZ) sm.bd.cnt[t] = 0;
        __syncthreads();
        int bbase = bid * cap;
        int bcnt = min(cursor[bid], cap);
        for (int base = 0; base < bcnt; base += 2048) {
            int i0 = base + t * 4;
            if (i0 + 3 < bcnt) {
                int4 p = *(const int4*)(packed + bbase + i0);
                atomicAdd(&sm.bd.cnt[p.x >> 17], 1);
                atomicAdd(&sm.bd.cnt[p.y >> 17], 1);
                atomicAdd(&sm.bd.cnt[p.z >> 17], 1);
                atomicAdd(&sm.bd.cnt[p.w >> 17], 1);
            } else {
                for (int i = i0; i < bcnt && i < i0 + 4; i++)
                    atomicAdd(&sm.bd.cnt[packed[bbase + i] >> 17], 1);
            }
        }
        int ovc = *ov_cursor;
        for (int i = t; i < ovc; i += 512) {
            int2 o = ovbuf[i];
            if ((o.y >> BSH) == bid) atomicAdd(&sm.bd.cnt[o.y & (BSZ - 1)], 1);
        }
        __syncthreads();
        int node = (bid << BSH) + t;
        if (t < BSZ && node < n) {
            float dv = rsqrtf((float)(sm.bd.cnt[t] + 1));  // +1 self-loop
            dinv[node] = dv;
            y[node] = dv * x[node];
        }
    }
    if (bid == 0 && t < 4 * HCH) {
        int c = t >> 6, j = t & 63;
        float acc = 0.f;
        for (int k = 0; k < HCH; k++) {
            float w = w1[k], b = b1[k], v = w2[k * HCH + j];
            if (c == 0)      acc += (w > 0.f) ? w * v : 0.f;
            else if (c == 1) acc += (w < 0.f) ? w * v : 0.f;
            else if (c == 2) acc += (w > 0.f) ? b * v : (w == 0.f ? fmaxf(b, 0.f) * v : 0.f);
            else             acc += (w < 0.f) ? b * v : (w == 0.f ? fmaxf(b, 0.f) * v : 0.f);
        }
        P[t] = acc;
        if (c >= 2) {  // |B| flag -> P[256] (zeroed by host memset)
            float f = fabsf(acc);
#pragma unroll
            for (int off = 32; off; off >>= 1) f += __shfl_xor(f, off, 64);
            if ((t & 63) == 0) atomicAdd(&P[4 * HCH], f);
        }
    }
    grid.sync();

    // ---------- phase 3: bagg1 -> val2 ----------
    if (bid < nb) {
        if (t < BSZ) sm.g1.acc[t] = 0.f;
        __syncthreads();
        int bbase = bid * cap;
        int bcnt = min(cursor[bid], cap);
        for (int base = 0; base < bcnt; base += 2048) {
            int i0 = base + t * 4;
            if (i0 + 3 < bcnt) {
                int4 p = *(const int4*)(packed + bbase + i0);
                float y0 = y[p.x & 0x1FFFF], y1 = y[p.y & 0x1FFFF];
                float y2 = y[p.z & 0x1FFFF], y3 = y[p.w & 0x1FFFF];
                lds_addf(&sm.g1.acc[p.x >> 17], y0);
                lds_addf(&sm.g1.acc[p.y >> 17], y1);
                lds_addf(&sm.g1.acc[p.z >> 17], y2);
                lds_addf(&sm.g1.acc[p.w >> 17], y3);
            } else {
                for (int i = i0; i < bcnt && i < i0 + 4; i++) {
                    int p = packed[bbase + i];
                    lds_addf(&sm.g1.acc[p >> 17], y[p & 0x1FFFF]);
                }
            }
        }
        int ovc = *ov_cursor;
        for (int i = t; i < ovc; i += 512) {
            int2 o = ovbuf[i];
            if ((o.y >> BSH) == bid) lds_addf(&sm.g1.acc[o.y & (BSZ - 1)], y[o.x]);
        }
        __syncthreads();
        int node = (bid << BSH) + t;
        if (t < BSZ && node < n) {
            float dv = dinv[node];
            float s = dv * (sm.g1.acc[t] + dv * x[node]);
            val2[node] = make_float2(dv * s, dv);
        }
    }
    grid.sync();

    // ---------- phase 4: bagg2 + epilogue -> out ----------
    if (bid >= nb) return;
    sm.g2.aa[t] = 0.f;
    sm.g2.cc[t] = 0.f;
    if (t < 4 * HCH) sm.g2.sP[t] = P[t];
    if (t >= 256 && t < 320) sm.g2.sb2[t - 256] = b2v[t - 256];
    if (t >= 320 && t < 384) sm.g2.swfc[t - 320] = wfc[t - 320];
    __syncthreads();
    bool useB = P[4 * HCH] != 0.f;
    {
        int bbase = bid * cap;
        int bcnt = min(cursor[bid], cap);
        for (int base = 0; base < bcnt; base += 2048) {
            int i0 = base + t * 4;
            if (i0 + 3 < bcnt) {
                int4 p = *(const int4*)(packed + bbase + i0);
                float2 v0 = val2[p.x & 0x1FFFF], v1 = val2[p.y & 0x1FFFF];
                float2 v2 = val2[p.z & 0x1FFFF], v3 = val2[p.w & 0x1FFFF];
                int o0 = (v0.x > 0.f ? 0 : BSZ) + (p.x >> 17);
                int o1 = (v1.x > 0.f ? 0 : BSZ) + (p.y >> 17);
                int o2 = (v2.x > 0.f ? 0 : BSZ) + (p.z >> 17);
                int o3 = (v3.x > 0.f ? 0 : BSZ) + (p.w >> 17);
                lds_addf(&sm.g2.aa[o0], v0.x); lds_addf(&sm.g2.aa[o1], v1.x);
                lds_addf(&sm.g2.aa[o2], v2.x); lds_addf(&sm.g2.aa[o3], v3.x);
                if (useB) {
                    lds_addf(&sm.g2.cc[o0], v0.y); lds_addf(&sm.g2.cc[o1], v1.y);
                    lds_addf(&sm.g2.cc[o2], v2.y); lds_addf(&sm.g2.cc[o3], v3.y);
                }
            } else {
                for (int i = i0; i < bcnt && i < i0 + 4; i++) {
                    int p = packed[bbase + i];
                    float2 v = val2[p & 0x1FFFF];
                    int off = (v.x > 0.f ? 0 : BSZ) + (p >> 17);
                    lds_addf(&sm.g2.aa[off], v.x);
                    if (useB) lds_addf(&sm.g2.cc[off], v.y);
                }
            }
        }
        int ovc = *ov_cursor;
        for (int i = t; i < ovc; i += 512) {
            int2 o = ovbuf[i];
            if ((o.y >> BSH) == bid) {
                float2 v = val2[o.x];
                int off = (v.x > 0.f ? 0 : BSZ) + (o.y & (BSZ - 1));
                lds_addf(&sm.g2.aa[off], v.x);
                if (useB) lds_addf(&sm.g2.cc[off], v.y);
            }
        }
    }
    __syncthreads();
    int node = (bid << BSH) + t;
    if (t >= BSZ || node >= n) return;
    float a_p = sm.g2.aa[t], a_m = sm.g2.aa[BSZ + t];
    float c_p = sm.g2.cc[t], c_m = sm.g2.cc[BSZ + t];
    float2 sv = val2[node];  // self-loop
    if (sv.x > 0.f) { a_p += sv.x; c_p += sv.y; }
    else            { a_m += sv.x; c_m += sv.y; }
    float dv = dinv[node];
    float acc = 0.f;
#pragma unroll 8
    for (int j = 0; j < HCH; j++) {
        float z = dv * (a_p * sm.g2.sP[j] + a_m * sm.g2.sP[HCH + j] +
                        c_p * sm.g2.sP[2 * HCH + j] + c_m * sm.g2.sP[3 * HCH + j]) +
                  sm.g2.sb2[j];
        z = fmaxf(z, 0.f);
        acc += z * sm.g2.swfc[j];
    }
    out[node] = acc + bfc[0];
}

extern "C" void kernel_launch(void* const* d_in, const int* in_sizes, int n_in,
                              void* d_out, int out_size, void* d_ws, size_t ws_size,
                              hipStream_t stream) {
    const float* x   = (const float*)d_in[0];
    const int*   ei  = (const int*)d_in[1];
    const float* w1  = (const float*)d_in[2];
    const float* b1  = (const float*)d_in[3];
    const float* w2  = (const float*)d_in[4];
    const float* b2  = (const float*)d_in[5];
    const float* wfc = (const float*)d_in[6];
    const float* bfc = (const float*)d_in[7];
    float* out = (float*)d_out;

    int n = in_sizes[0];      // 100000
    int e = in_sizes[1] / 2;  // 1600000
    const int* src = ei;
    const int* dst = ei + e;

    int nb = (n + BSZ - 1) >> BSH;              // 391 buckets
    int nchunk = (e + CHUNK - 1) / CHUNK;       // 391 chunks
    int avg = (e + nb - 1) / nb;
    int cap = ((avg + avg / 4 + 64) + 15) & ~15;  // fixed bucket capacity

    auto al = [](size_t v) { return (v + 255) & ~(size_t)255; };
    char* ws = (char*)d_ws;
    size_t o = 0;
    int* cursor    = (int*)(ws + o);  o += (size_t)NBMAX * 4;
    int* ov_cursor = (int*)(ws + o);  o += 256;
    float* P       = (float*)(ws + o); o += (4 * HCH + 8) * 4;
    size_t zbytes = o;                 // memset covers cursor + ov_cursor + P
    o = al(o);
    float* dinv  = (float*)(ws + o);  o = al(o + (size_t)n * 4);
    float* y     = (float*)(ws + o);  o = al(o + (size_t)n * 4);
    float2* val2 = (float2*)(ws + o); o = al(o + (size_t)n * 8);
    int* packed  = (int*)(ws + o);    o = al(o + (size_t)nb * cap * 4);
    int2* ovbuf  = (int2*)(ws + o);   o = al(o + (size_t)e * 8);
    (void)ws_size;

    int grid = nb > nchunk ? nb : nchunk;  // 391

    hipMemsetAsync(ws, 0, zbytes, stream);
    void* args[] = {&src, &dst, &e, &n, &nb, &nchunk, &cap,
                    &cursor, &ov_cursor, &ovbuf, &packed,
                    &x, &dinv, &y, &val2,
                    &w1, &b1, &w2, &P, &b2, &wfc, &bfc, &out};
    hipLaunchCooperativeKernel((void*)k_fused, dim3(grid), dim3(512), args, 0, stream);
}

// Round 9
// 139.679 us; speedup vs baseline: 2.3968x; 2.2419x over previous
//
#include <hip/hip_runtime.h>

// GCN N=100k, E=1.6M, H=64 — algebraic collapse + bucket-LDS scatter.
//
// Math (layer-1 input is [N,1] => per-node hidden state is a scalar function):
//   s[d] = dinv[d]*(sum_{src->d} dinv[src]*x[src] + dinv[d]*x[d])
//   relu(s*w1+b1) @ w2 = s*P^{sign(s)} + B^{sign(s)}   (P±,B± 64-vecs; B=0 for b1=0)
//   layer-2 scalars a±[d], c±[d];
//   out[d] = relu(dinv[d]*(a+P+ + a-P- + c+B+ + c-B-) + b2) . wfc + bfc
//
// Hard-won rules:
//   * global atomics & scattered global stores cost ~60B memory-side traffic each
//     (rounds 1,3,7) — ALL scatter-accumulate must be LDS inside bucket workgroups.
//   * XCD-replicated accumulators do NOT help (atomics are device-scope,
//     memory-side regardless of replica locality) — round 7.
//   * cooperative grid.sync is worse than dispatch boundaries (round 8).
//
// Pipeline (5 dispatches):
//   memset(5.4KB) -> k_place (bin edges by dst>>7 into fixed-cap regions, LDS
//   stash, 1 cursor atomic per (chunk,bucket) run, exact overflow spill)
//   -> k_bdeg (per-bucket LDS histogram -> dinv, y; block 0 folds P± precompute)
//   -> k_bagg1 (LDS accumulate y[src] -> val2) -> k_bagg2 (sign-split LDS
//   accumulate + fused epilogue -> out).

#define HCH 64
#define CHUNK 4096
#define BSH 7
#define BSZ 128          // nodes per bucket
#define NBMAX 1024

__device__ __forceinline__ void lds_addf(float* p, float v) {
    __hip_atomic_fetch_add(p, v, __ATOMIC_RELAXED, __HIP_MEMORY_SCOPE_WORKGROUP);
}

// 1024 threads, 4 edges/thread: stash chunk in LDS, reserve runs, scatter.
__global__ __launch_bounds__(1024) void k_place(const int* __restrict__ src,
                                                const int* __restrict__ dst, int e,
                                                int nb, int cap,
                                                int* __restrict__ cursor,
                                                int* __restrict__ ov_cursor,
                                                int* __restrict__ packed,
                                                int2* __restrict__ ovbuf) {
    __shared__ int h[NBMAX];
    __shared__ int basel[NBMAX];
    __shared__ int avail[NBMAX];
    __shared__ int lpv[CHUNK];
    __shared__ short lb[CHUNK];
    int t = threadIdx.x;
    if (t < nb) h[t] = 0;
    __syncthreads();
    int cbase = blockIdx.x * CHUNK;
    int rem = min(e - cbase, CHUNK);
    int li = t * 4;
    if (li + 3 < rem) {
        int4 s4 = *(const int4*)(src + cbase + li);
        int4 d4 = *(const int4*)(dst + cbase + li);
#pragma unroll
        for (int q = 0; q < 4; q++) {
            int sv = (q == 0) ? s4.x : (q == 1) ? s4.y : (q == 2) ? s4.z : s4.w;
            int dv = (q == 0) ? d4.x : (q == 1) ? d4.y : (q == 2) ? d4.z : d4.w;
            int b = dv >> BSH;
            atomicAdd(&h[b], 1);
            lpv[li + q] = sv | ((dv & (BSZ - 1)) << 17);
            lb[li + q] = (short)b;
        }
    } else {
        for (int q = li; q < rem && q < li + 4; q++) {
            int sv = src[cbase + q], dv = dst[cbase + q];
            int b = dv >> BSH;
            atomicAdd(&h[b], 1);
            lpv[q] = sv | ((dv & (BSZ - 1)) << 17);
            lb[q] = (short)b;
        }
    }
    __syncthreads();
    if (t < nb) {
        int my = h[t];
        int av = 0, base = 0;
        if (my) {
            base = atomicAdd(&cursor[t], my);   // bucket-relative cursor
            int room = cap - base;
            av = room < 0 ? 0 : (room > my ? my : room);
        }
        basel[t] = t * cap + base;
        avail[t] = av;
        h[t] = 0;  // reuse as local run cursor
    }
    __syncthreads();
    int lim = min(rem, li + 4);
    for (int q = li; q < lim; q++) {
        int b = lb[q];
        int pv = lpv[q];
        int loc = atomicAdd(&h[b], 1);
        if (loc < avail[b]) {
            packed[basel[b] + loc] = pv;
        } else {
            int op = atomicAdd(ov_cursor, 1);
            ovbuf[op] = make_int2(pv & 0x1FFFF, (b << BSH) | (pv >> 17));
        }
    }
}

// per bucket: LDS histogram of local dst -> deg -> dinv, y = dinv*x.
// Block 0 threads 128..383 also compute P[0..63]=P+, P[64..127]=P-,
// P[128..191]=B+, P[192..255]=B-, and atomically add |B| into P[256] (flag).
__global__ __launch_bounds__(512) void k_bdeg(const int* __restrict__ packed,
                                              const int* __restrict__ cursor,
                                              const int* __restrict__ ov_cursor,
                                              const int2* __restrict__ ovbuf,
                                              int cap, const float* __restrict__ x, int n,
                                              float* __restrict__ dinv,
                                              float* __restrict__ y,
                                              const float* __restrict__ w1,
                                              const float* __restrict__ b1,
                                              const float* __restrict__ w2,
                                              float* __restrict__ P) {
    __shared__ int cnt[BSZ];
    int bk = blockIdx.x, t = threadIdx.x;
    int bbase = bk * cap;
    int bcnt = min(cursor[bk], cap);
    if (t < BSZ) cnt[t] = 0;
    __syncthreads();
    for (int base = 0; base < bcnt; base += 2048) {
        int i0 = base + t * 4;
        if (i0 + 3 < bcnt) {
            int4 p = *(const int4*)(packed + bbase + i0);
            atomicAdd(&cnt[p.x >> 17], 1);
            atomicAdd(&cnt[p.y >> 17], 1);
            atomicAdd(&cnt[p.z >> 17], 1);
            atomicAdd(&cnt[p.w >> 17], 1);
        } else {
            for (int i = i0; i < bcnt && i < i0 + 4; i++)
                atomicAdd(&cnt[packed[bbase + i] >> 17], 1);
        }
    }
    int ovc = *ov_cursor;
    for (int i = t; i < ovc; i += 512) {
        int2 o = ovbuf[i];
        if ((o.y >> BSH) == bk) atomicAdd(&cnt[o.y & (BSZ - 1)], 1);
    }
    __syncthreads();
    int node = (bk << BSH) + t;
    if (t < BSZ && node < n) {
        float dv = rsqrtf((float)(cnt[t] + 1));  // +1 self-loop
        dinv[node] = dv;
        y[node] = dv * x[node];
    }
    if (bk == 0 && t >= 128 && t < 384) {
        int tt = t - 128;
        int c = tt >> 6, j = tt & 63;
        float acc = 0.f;
        for (int k = 0; k < HCH; k++) {
            float w = w1[k], b = b1[k], v = w2[k * HCH + j];
            if (c == 0)      acc += (w > 0.f) ? w * v : 0.f;
            else if (c == 1) acc += (w < 0.f) ? w * v : 0.f;
            else if (c == 2) acc += (w > 0.f) ? b * v : (w == 0.f ? fmaxf(b, 0.f) * v : 0.f);
            else             acc += (w < 0.f) ? b * v : (w == 0.f ? fmaxf(b, 0.f) * v : 0.f);
        }
        P[c * HCH + j] = acc;
        if (c >= 2) {  // |B| flag -> P[256] (zeroed by host memset)
            float f = fabsf(acc);
#pragma unroll
            for (int off = 32; off; off >>= 1) f += __shfl_xor(f, off, 64);
            if ((t & 63) == 0) atomicAdd(&P[4 * HCH], f);
        }
    }
}

// per bucket: acc[localdst] += y[src] -> s -> val2 = (dinv*s, dinv)
__global__ __launch_bounds__(512) void k_bagg1(const int* __restrict__ packed,
                                               const int* __restrict__ cursor,
                                               const int* __restrict__ ov_cursor,
                                               const int2* __restrict__ ovbuf,
                                               int cap, const float* __restrict__ x,
                                               const float* __restrict__ dinv,
                                               const float* __restrict__ y, int n,
                                               float2* __restrict__ val2) {
    __shared__ float acc[BSZ];
    int bk = blockIdx.x, t = threadIdx.x;
    int bbase = bk * cap;
    int bcnt = min(cursor[bk], cap);
    if (t < BSZ) acc[t] = 0.f;
    __syncthreads();
    for (int base = 0; base < bcnt; base += 2048) {
        int i0 = base + t * 4;
        if (i0 + 3 < bcnt) {
            int4 p = *(const int4*)(packed + bbase + i0);
            float y0 = y[p.x & 0x1FFFF], y1 = y[p.y & 0x1FFFF];
            float y2 = y[p.z & 0x1FFFF], y3 = y[p.w & 0x1FFFF];
            lds_addf(&acc[p.x >> 17], y0);
            lds_addf(&acc[p.y >> 17], y1);
            lds_addf(&acc[p.z >> 17], y2);
            lds_addf(&acc[p.w >> 17], y3);
        } else {
            for (int i = i0; i < bcnt && i < i0 + 4; i++) {
                int p = packed[bbase + i];
                lds_addf(&acc[p >> 17], y[p & 0x1FFFF]);
            }
        }
    }
    int ovc = *ov_cursor;
    for (int i = t; i < ovc; i += 512) {
        int2 o = ovbuf[i];
        if ((o.y >> BSH) == bk) lds_addf(&acc[o.y & (BSZ - 1)], y[o.x]);
    }
    __syncthreads();
    int node = (bk << BSH) + t;
    if (t < BSZ && node < n) {
        float dv = dinv[node];
        float s = dv * (acc[t] + dv * x[node]);
        val2[node] = make_float2(dv * s, dv);
    }
}

// per bucket: sign-split LDS accumulate of val2[src] + fused epilogue -> out
__global__ __launch_bounds__(512) void k_bagg2(const int* __restrict__ packed,
                                               const int* __restrict__ cursor,
                                               const int* __restrict__ ov_cursor,
                                               const int2* __restrict__ ovbuf,
                                               int cap, const float2* __restrict__ val2,
                                               const float* __restrict__ dinv,
                                               const float* __restrict__ P,
                                               const float* __restrict__ b2,
                                               const float* __restrict__ wfc,
                                               const float* __restrict__ bfc,
                                               float* __restrict__ out, int n) {
    __shared__ float aa[2 * BSZ];   // [0..BSZ): positive, [BSZ..2BSZ): negative
    __shared__ float cc[2 * BSZ];
    __shared__ float sP[4 * HCH], sb2[HCH], swfc[HCH];
    int bk = blockIdx.x, t = threadIdx.x;
    int bbase = bk * cap;
    int bcnt = min(cursor[bk], cap);
    if (t < 2 * BSZ) { aa[t] = 0.f; cc[t] = 0.f; }
    if (t < 4 * HCH) sP[t] = P[t];
    if (t >= 256 && t < 320) sb2[t - 256] = b2[t - 256];
    if (t >= 320 && t < 384) swfc[t - 320] = wfc[t - 320];
    __syncthreads();
    bool useB = P[4 * HCH] != 0.f;
    for (int base = 0; base < bcnt; base += 2048) {
        int i0 = base + t * 4;
        if (i0 + 3 < bcnt) {
            int4 p = *(const int4*)(packed + bbase + i0);
            float2 v0 = val2[p.x & 0x1FFFF], v1 = val2[p.y & 0x1FFFF];
            float2 v2 = val2[p.z & 0x1FFFF], v3 = val2[p.w & 0x1FFFF];
            int o0 = (v0.x > 0.f ? 0 : BSZ) + (p.x >> 17);
            int o1 = (v1.x > 0.f ? 0 : BSZ) + (p.y >> 17);
            int o2 = (v2.x > 0.f ? 0 : BSZ) + (p.z >> 17);
            int o3 = (v3.x > 0.f ? 0 : BSZ) + (p.w >> 17);
            lds_addf(&aa[o0], v0.x); lds_addf(&aa[o1], v1.x);
            lds_addf(&aa[o2], v2.x); lds_addf(&aa[o3], v3.x);
            if (useB) {
                lds_addf(&cc[o0], v0.y); lds_addf(&cc[o1], v1.y);
                lds_addf(&cc[o2], v2.y); lds_addf(&cc[o3], v3.y);
            }
        } else {
            for (int i = i0; i < bcnt && i < i0 + 4; i++) {
                int p = packed[bbase + i];
                float2 v = val2[p & 0x1FFFF];
                int off = (v.x > 0.f ? 0 : BSZ) + (p >> 17);
                lds_addf(&aa[off], v.x);
                if (useB) lds_addf(&cc[off], v.y);
            }
        }
    }
    int ovc = *ov_cursor;
    for (int i = t; i < ovc; i += 512) {
        int2 o = ovbuf[i];
        if ((o.y >> BSH) == bk) {
            float2 v = val2[o.x];
            int off = (v.x > 0.f ? 0 : BSZ) + (o.y & (BSZ - 1));
            lds_addf(&aa[off], v.x);
            if (useB) lds_addf(&cc[off], v.y);
        }
    }
    __syncthreads();
    int node = (bk << BSH) + t;
    if (t >= BSZ || node >= n) return;
    float a_p = aa[t], a_m = aa[BSZ + t], c_p = cc[t], c_m = cc[BSZ + t];
    float2 sv = val2[node];  // self-loop
    if (sv.x > 0.f) { a_p += sv.x; c_p += sv.y; }
    else            { a_m += sv.x; c_m += sv.y; }
    float dv = dinv[node];
    float acc = 0.f;
#pragma unroll 8
    for (int j = 0; j < HCH; j++) {
        float z = dv * (a_p * sP[j] + a_m * sP[HCH + j] +
                        c_p * sP[2 * HCH + j] + c_m * sP[3 * HCH + j]) + sb2[j];
        z = fmaxf(z, 0.f);
        acc += z * swfc[j];
    }
    out[node] = acc + bfc[0];
}

extern "C" void kernel_launch(void* const* d_in, const int* in_sizes, int n_in,
                              void* d_out, int out_size, void* d_ws, size_t ws_size,
                              hipStream_t stream) {
    const float* x   = (const float*)d_in[0];
    const int*   ei  = (const int*)d_in[1];
    const float* w1  = (const float*)d_in[2];
    const float* b1  = (const float*)d_in[3];
    const float* w2  = (const float*)d_in[4];
    const float* b2  = (const float*)d_in[5];
    const float* wfc = (const float*)d_in[6];
    const float* bfc = (const float*)d_in[7];
    float* out = (float*)d_out;

    const int n = in_sizes[0];      // 100000
    const int e = in_sizes[1] / 2;  // 1600000
    const int* src = ei;
    const int* dst = ei + e;

    const int nb = (n + BSZ - 1) >> BSH;          // 782 buckets
    int avg = (e + nb - 1) / nb;                  // ~2047
    int cap = ((avg + avg / 4 + 64) + 15) & ~15;  // ~13 sigma headroom, 16-aligned

    auto al = [](size_t v) { return (v + 255) & ~(size_t)255; };
    char* ws = (char*)d_ws;
    size_t o = 0;
    int* cursor    = (int*)(ws + o);  o += (size_t)NBMAX * 4;
    int* ov_cursor = (int*)(ws + o);  o += 256;
    float* P       = (float*)(ws + o); o += (4 * HCH + 8) * 4;
    size_t zbytes = o;                 // single memset: cursors + ov + P/flag
    o = al(o);
    float* dinv  = (float*)(ws + o);  o = al(o + (size_t)n * 4);
    float* y     = (float*)(ws + o);  o = al(o + (size_t)n * 4);
    float2* val2 = (float2*)(ws + o); o = al(o + (size_t)n * 8);
    int* packed  = (int*)(ws + o);    o = al(o + (size_t)nb * cap * 4);
    int2* ovbuf  = (int2*)(ws + o);   o = al(o + (size_t)e * 8);
    (void)ws_size;

    const int nchunk = (e + CHUNK - 1) / CHUNK;  // 391 chunks

    hipMemsetAsync(ws, 0, zbytes, stream);
    k_place<<<nchunk, 1024, 0, stream>>>(src, dst, e, nb, cap, cursor, ov_cursor,
                                         packed, ovbuf);
    k_bdeg<<<nb, 512, 0, stream>>>(packed, cursor, ov_cursor, ovbuf, cap, x, n,
                                   dinv, y, w1, b1, w2, P);
    k_bagg1<<<nb, 512, 0, stream>>>(packed, cursor, ov_cursor, ovbuf, cap, x, dinv, y,
                                    n, val2);
    k_bagg2<<<nb, 512, 0, stream>>>(packed, cursor, ov_cursor, ovbuf, cap, val2, dinv,
                                    P, b2, wfc, bfc, out, n);
}

// Round 10
// 138.171 us; speedup vs baseline: 2.4230x; 1.0109x over previous
//
#include <hip/hip_runtime.h>

// GCN N=100k, E=1.6M, H=64 — algebraic collapse + bucket-LDS scatter.
//
// Math (layer-1 input is [N,1] => per-node hidden state is a scalar function):
//   s[d] = dinv[d]*(sum_{src->d} dinv[src]*x[src] + dinv[d]*x[d])
//   relu(s*w1+b1) @ w2 = s*P^{sign(s)} + B^{sign(s)}   (P±,B± 64-vecs; B=0 for b1=0)
//   layer-2 scalars a±[d], c±[d];
//   out[d] = relu(dinv[d]*(a+P+ + a-P- + c+B+ + c-B-) + b2) . wfc + bfc
//
// Hard-won rules:
//   * scattered global stores/atomics ~60B memory-side each (rounds 1,3,7):
//     scatter-accumulate must be LDS; contended cursor atomics must be minimized.
//   * XCD-replicated accumulators don't help (device-scope atomics) — round 7.
//   * cooperative grid.sync worse than dispatch boundaries — round 8.
//
// k_place: CHUNK=8192 @1024thr, edges in REGISTERS across the barrier; the
// phase-1 histogram atomic's return value IS the scatter slot (no 2nd pass).
// Reservations = 196 chunks x 391 buckets = 77K atomics (was 306K).

#define HCH 64
#define CHUNK 8192
#define BSH 8
#define BSZ 256          // nodes per bucket
#define NBMAX 512

__device__ __forceinline__ void lds_addf(float* p, float v) {
    __hip_atomic_fetch_add(p, v, __ATOMIC_RELAXED, __HIP_MEMORY_SCOPE_WORKGROUP);
}

__global__ __launch_bounds__(1024) void k_place(const int* __restrict__ src,
                                                const int* __restrict__ dst, int e,
                                                int nb, int cap,
                                                int* __restrict__ cursor,
                                                int* __restrict__ ov_cursor,
                                                int* __restrict__ packed,
                                                int2* __restrict__ ovbuf) {
    __shared__ int h[NBMAX];
    __shared__ int basel[NBMAX];
    __shared__ int avail[NBMAX];
    int t = threadIdx.x;
    if (t < nb) h[t] = 0;
    __syncthreads();
    int cbase = blockIdx.x * CHUNK;
    int rem = min(e - cbase, CHUNK);

    int pv[8], bb[8], lc[8];
    bool ok[8];
#pragma unroll
    for (int g = 0; g < 2; g++) {
        int i0 = g * 4096 + t * 4;         // coalesced int4 across the block
        if (i0 + 3 < rem) {
            int4 s4 = *(const int4*)(src + cbase + i0);
            int4 d4 = *(const int4*)(dst + cbase + i0);
#pragma unroll
            for (int q = 0; q < 4; q++) {
                int k = g * 4 + q;
                int sv = (q == 0) ? s4.x : (q == 1) ? s4.y : (q == 2) ? s4.z : s4.w;
                int dv = (q == 0) ? d4.x : (q == 1) ? d4.y : (q == 2) ? d4.z : d4.w;
                int b = dv >> BSH;
                ok[k] = true;
                bb[k] = b;
                pv[k] = sv | ((dv & (BSZ - 1)) << 17);
                lc[k] = atomicAdd(&h[b], 1);   // unique slot within (chunk,bucket)
            }
        } else {
#pragma unroll
            for (int q = 0; q < 4; q++) {
                int k = g * 4 + q;
                int i = i0 + q;
                ok[k] = i < rem;
                if (ok[k]) {
                    int sv = src[cbase + i], dv = dst[cbase + i];
                    int b = dv >> BSH;
                    bb[k] = b;
                    pv[k] = sv | ((dv & (BSZ - 1)) << 17);
                    lc[k] = atomicAdd(&h[b], 1);
                }
            }
        }
    }
    __syncthreads();
    if (t < nb) {
        int my = h[t];
        int av = 0, base = 0;
        if (my) {
            base = atomicAdd(&cursor[t], my);   // bucket-relative cursor
            int room = cap - base;
            av = room < 0 ? 0 : (room > my ? my : room);
        }
        basel[t] = t * cap + base;
        avail[t] = av;
    }
    __syncthreads();
#pragma unroll
    for (int k = 0; k < 8; k++) {
        if (!ok[k]) continue;
        int b = bb[k];
        if (lc[k] < avail[b]) {
            packed[basel[b] + lc[k]] = pv[k];
        } else {
            int op = atomicAdd(ov_cursor, 1);
            ovbuf[op] = make_int2(pv[k] & 0x1FFFF, (b << BSH) | (pv[k] >> 17));
        }
    }
}

// per bucket: LDS histogram of local dst -> deg -> dinv, y = dinv*x.
// Block 0 threads 128..383 also fold the P±/B± precompute:
// P[0..63]=P+, P[64..127]=P-, P[128..191]=B+, P[192..255]=B-, P[256]=|B| flag.
__global__ __launch_bounds__(512) void k_bdeg(const int* __restrict__ packed,
                                              const int* __restrict__ cursor,
                                              const int* __restrict__ ov_cursor,
                                              const int2* __restrict__ ovbuf,
                                              int cap, const float* __restrict__ x, int n,
                                              float* __restrict__ dinv,
                                              float* __restrict__ y,
                                              const float* __restrict__ w1,
                                              const float* __restrict__ b1,
                                              const float* __restrict__ w2,
                                              float* __restrict__ P) {
    __shared__ int cnt[BSZ];
    int bk = blockIdx.x, t = threadIdx.x;
    int bbase = bk * cap;
    int bcnt = min(cursor[bk], cap);
    if (t < BSZ) cnt[t] = 0;
    __syncthreads();
    for (int base = 0; base < bcnt; base += 2048) {
        int i0 = base + t * 4;
        if (i0 + 3 < bcnt) {
            int4 p = *(const int4*)(packed + bbase + i0);
            atomicAdd(&cnt[p.x >> 17], 1);
            atomicAdd(&cnt[p.y >> 17], 1);
            atomicAdd(&cnt[p.z >> 17], 1);
            atomicAdd(&cnt[p.w >> 17], 1);
        } else {
            for (int i = i0; i < bcnt && i < i0 + 4; i++)
                atomicAdd(&cnt[packed[bbase + i] >> 17], 1);
        }
    }
    int ovc = *ov_cursor;
    for (int i = t; i < ovc; i += 512) {
        int2 o = ovbuf[i];
        if ((o.y >> BSH) == bk) atomicAdd(&cnt[o.y & (BSZ - 1)], 1);
    }
    __syncthreads();
    int node = (bk << BSH) + t;
    if (t < BSZ && node < n) {
        float dv = rsqrtf((float)(cnt[t] + 1));  // +1 self-loop
        dinv[node] = dv;
        y[node] = dv * x[node];
    }
    if (bk == 0 && t >= 128 && t < 384) {
        int tt = t - 128;
        int c = tt >> 6, j = tt & 63;
        float acc = 0.f;
        for (int k = 0; k < HCH; k++) {
            float w = w1[k], b = b1[k], v = w2[k * HCH + j];
            if (c == 0)      acc += (w > 0.f) ? w * v : 0.f;
            else if (c == 1) acc += (w < 0.f) ? w * v : 0.f;
            else if (c == 2) acc += (w > 0.f) ? b * v : (w == 0.f ? fmaxf(b, 0.f) * v : 0.f);
            else             acc += (w < 0.f) ? b * v : (w == 0.f ? fmaxf(b, 0.f) * v : 0.f);
        }
        P[c * HCH + j] = acc;
        if (c >= 2) {  // |B| flag -> P[256] (zeroed by host memset)
            float f = fabsf(acc);
#pragma unroll
            for (int off = 32; off; off >>= 1) f += __shfl_xor(f, off, 64);
            if ((t & 63) == 0) atomicAdd(&P[4 * HCH], f);
        }
    }
}

// per bucket: acc[localdst] += y[src] -> s -> val2 = (dinv*s, dinv)
__global__ __launch_bounds__(512) void k_bagg1(const int* __restrict__ packed,
                                               const int* __restrict__ cursor,
                                               const int* __restrict__ ov_cursor,
                                               const int2* __restrict__ ovbuf,
                                               int cap, const float* __restrict__ x,
                                               const float* __restrict__ dinv,
                                               const float* __restrict__ y, int n,
                                               float2* __restrict__ val2) {
    __shared__ float acc[BSZ];
    int bk = blockIdx.x, t = threadIdx.x;
    int bbase = bk * cap;
    int bcnt = min(cursor[bk], cap);
    if (t < BSZ) acc[t] = 0.f;
    __syncthreads();
    for (int base = 0; base < bcnt; base += 2048) {
        int i0 = base + t * 4;
        if (i0 + 3 < bcnt) {
            int4 p = *(const int4*)(packed + bbase + i0);
            float y0 = y[p.x & 0x1FFFF], y1 = y[p.y & 0x1FFFF];
            float y2 = y[p.z & 0x1FFFF], y3 = y[p.w & 0x1FFFF];
            lds_addf(&acc[p.x >> 17], y0);
            lds_addf(&acc[p.y >> 17], y1);
            lds_addf(&acc[p.z >> 17], y2);
            lds_addf(&acc[p.w >> 17], y3);
        } else {
            for (int i = i0; i < bcnt && i < i0 + 4; i++) {
                int p = packed[bbase + i];
                lds_addf(&acc[p >> 17], y[p & 0x1FFFF]);
            }
        }
    }
    int ovc = *ov_cursor;
    for (int i = t; i < ovc; i += 512) {
        int2 o = ovbuf[i];
        if ((o.y >> BSH) == bk) lds_addf(&acc[o.y & (BSZ - 1)], y[o.x]);
    }
    __syncthreads();
    int node = (bk << BSH) + t;
    if (t < BSZ && node < n) {
        float dv = dinv[node];
        float s = dv * (acc[t] + dv * x[node]);
        val2[node] = make_float2(dv * s, dv);
    }
}

// per bucket: sign-split LDS accumulate of val2[src] + fused epilogue -> out
__global__ __launch_bounds__(512) void k_bagg2(const int* __restrict__ packed,
                                               const int* __restrict__ cursor,
                                               const int* __restrict__ ov_cursor,
                                               const int2* __restrict__ ovbuf,
                                               int cap, const float2* __restrict__ val2,
                                               const float* __restrict__ dinv,
                                               const float* __restrict__ P,
                                               const float* __restrict__ b2,
                                               const float* __restrict__ wfc,
                                               const float* __restrict__ bfc,
                                               float* __restrict__ out, int n) {
    __shared__ float aa[2 * BSZ];   // [0..BSZ): positive, [BSZ..2BSZ): negative
    __shared__ float cc[2 * BSZ];
    __shared__ float sP[4 * HCH], sb2[HCH], swfc[HCH];
    int bk = blockIdx.x, t = threadIdx.x;
    int bbase = bk * cap;
    int bcnt = min(cursor[bk], cap);
    aa[t] = 0.f; cc[t] = 0.f;       // t<512 covers 2*BSZ
    if (t < 4 * HCH) sP[t] = P[t];
    if (t >= 256 && t < 320) sb2[t - 256] = b2[t - 256];
    if (t >= 320 && t < 384) swfc[t - 320] = wfc[t - 320];
    __syncthreads();
    bool useB = P[4 * HCH] != 0.f;
    for (int base = 0; base < bcnt; base += 2048) {
        int i0 = base + t * 4;
        if (i0 + 3 < bcnt) {
            int4 p = *(const int4*)(packed + bbase + i0);
            float2 v0 = val2[p.x & 0x1FFFF], v1 = val2[p.y & 0x1FFFF];
            float2 v2 = val2[p.z & 0x1FFFF], v3 = val2[p.w & 0x1FFFF];
            int o0 = (v0.x > 0.f ? 0 : BSZ) + (p.x >> 17);
            int o1 = (v1.x > 0.f ? 0 : BSZ) + (p.y >> 17);
            int o2 = (v2.x > 0.f ? 0 : BSZ) + (p.z >> 17);
            int o3 = (v3.x > 0.f ? 0 : BSZ) + (p.w >> 17);
            lds_addf(&aa[o0], v0.x); lds_addf(&aa[o1], v1.x);
            lds_addf(&aa[o2], v2.x); lds_addf(&aa[o3], v3.x);
            if (useB) {
                lds_addf(&cc[o0], v0.y); lds_addf(&cc[o1], v1.y);
                lds_addf(&cc[o2], v2.y); lds_addf(&cc[o3], v3.y);
            }
        } else {
            for (int i = i0; i < bcnt && i < i0 + 4; i++) {
                int p = packed[bbase + i];
                float2 v = val2[p & 0x1FFFF];
                int off = (v.x > 0.f ? 0 : BSZ) + (p >> 17);
                lds_addf(&aa[off], v.x);
                if (useB) lds_addf(&cc[off], v.y);
            }
        }
    }
    int ovc = *ov_cursor;
    for (int i = t; i < ovc; i += 512) {
        int2 o = ovbuf[i];
        if ((o.y >> BSH) == bk) {
            float2 v = val2[o.x];
            int off = (v.x > 0.f ? 0 : BSZ) + (o.y & (BSZ - 1));
            lds_addf(&aa[off], v.x);
            if (useB) lds_addf(&cc[off], v.y);
        }
    }
    __syncthreads();
    int node = (bk << BSH) + t;
    if (t >= BSZ || node >= n) return;
    float a_p = aa[t], a_m = aa[BSZ + t], c_p = cc[t], c_m = cc[BSZ + t];
    float2 sv = val2[node];  // self-loop
    if (sv.x > 0.f) { a_p += sv.x; c_p += sv.y; }
    else            { a_m += sv.x; c_m += sv.y; }
    float dv = dinv[node];
    float acc = 0.f;
#pragma unroll 8
    for (int j = 0; j < HCH; j++) {
        float z = dv * (a_p * sP[j] + a_m * sP[HCH + j] +
                        c_p * sP[2 * HCH + j] + c_m * sP[3 * HCH + j]) + sb2[j];
        z = fmaxf(z, 0.f);
        acc += z * swfc[j];
    }
    out[node] = acc + bfc[0];
}

extern "C" void kernel_launch(void* const* d_in, const int* in_sizes, int n_in,
                              void* d_out, int out_size, void* d_ws, size_t ws_size,
                              hipStream_t stream) {
    const float* x   = (const float*)d_in[0];
    const int*   ei  = (const int*)d_in[1];
    const float* w1  = (const float*)d_in[2];
    const float* b1  = (const float*)d_in[3];
    const float* w2  = (const float*)d_in[4];
    const float* b2  = (const float*)d_in[5];
    const float* wfc = (const float*)d_in[6];
    const float* bfc = (const float*)d_in[7];
    float* out = (float*)d_out;

    const int n = in_sizes[0];      // 100000
    const int e = in_sizes[1] / 2;  // 1600000
    const int* src = ei;
    const int* dst = ei + e;

    const int nb = (n + BSZ - 1) >> BSH;          // 391 buckets
    int avg = (e + nb - 1) / nb;                  // ~4093
    int cap = ((avg + avg / 8 + 128) + 15) & ~15; // ~10 sigma headroom, exact ov path

    auto al = [](size_t v) { return (v + 255) & ~(size_t)255; };
    char* ws = (char*)d_ws;
    size_t o = 0;
    int* cursor    = (int*)(ws + o);  o += (size_t)NBMAX * 4;
    int* ov_cursor = (int*)(ws + o);  o += 256;
    float* P       = (float*)(ws + o); o += (4 * HCH + 8) * 4;
    size_t zbytes = o;                 // single memset: cursors + ov + P/flag
    o = al(o);
    float* dinv  = (float*)(ws + o);  o = al(o + (size_t)n * 4);
    float* y     = (float*)(ws + o);  o = al(o + (size_t)n * 4);
    float2* val2 = (float2*)(ws + o); o = al(o + (size_t)n * 8);
    int* packed  = (int*)(ws + o);    o = al(o + (size_t)nb * cap * 4);
    int2* ovbuf  = (int2*)(ws + o);   o = al(o + (size_t)e * 8);
    (void)ws_size;

    const int nchunk = (e + CHUNK - 1) / CHUNK;  // 196 chunks

    hipMemsetAsync(ws, 0, zbytes, stream);
    k_place<<<nchunk, 1024, 0, stream>>>(src, dst, e, nb, cap, cursor, ov_cursor,
                                         packed, ovbuf);
    k_bdeg<<<nb, 512, 0, stream>>>(packed, cursor, ov_cursor, ovbuf, cap, x, n,
                                   dinv, y, w1, b1, w2, P);
    k_bagg1<<<nb, 512, 0, stream>>>(packed, cursor, ov_cursor, ovbuf, cap, x, dinv, y,
                                    n, val2);
    k_bagg2<<<nb, 512, 0, stream>>>(packed, cursor, ov_cursor, ovbuf, cap, val2, dinv,
                                    P, b2, wfc, bfc, out, n);
}